// Round 7
// baseline (129.828 us; speedup 1.0000x reference)
//
#include <hip/hip_runtime.h>

#define DEPTH 11
#define D 1024
#define H 32
#define OW 1024
#define B 4096
#define N_LEAVES 2048
#define N_NODES 2047
#define SMAX 4
#define MAX_ITEMS 3072
#define NBLK 512
#define MAXK 6   // ceil(MAX_ITEMS / NBLK)

typedef __attribute__((address_space(3))) void lds_void;
typedef const __attribute__((address_space(1))) void glb_void;

#define SB __builtin_amdgcn_sched_barrier(0)
#define WAITV(N) do { asm volatile("s_waitcnt vmcnt(" #N ")" ::: "memory"); SB; } while (0)
#define WAITLG0  do { asm volatile("s_waitcnt lgkmcnt(0)" ::: "memory"); SB; } while (0)
#define BARRIER  do { WAITLG0; __builtin_amdgcn_s_barrier(); \
                      asm volatile("" ::: "memory"); SB; } while (0)

// ---------------------------------------------------------------------------
// Kernel 1: tree descent. One wave per sample; f64 dot to match the np f64
// reference on the hard >=0 branch decision.
// ---------------------------------------------------------------------------
__global__ __launch_bounds__(256) void descent_kernel(
    const float* __restrict__ x, const float* __restrict__ nw,
    const float* __restrict__ nb, int* __restrict__ leaf,
    int* __restrict__ rnk, int* __restrict__ count)
{
    int lane = threadIdx.x & 63;
    int wv   = threadIdx.x >> 6;
    int samp = blockIdx.x * 4 + wv;

    const float4* xp = (const float4*)(x + (size_t)samp * D);
    float4 xf[4];
#pragma unroll
    for (int k = 0; k < 4; k++) xf[k] = xp[lane + 64 * k];

    int node = 0;
#pragma unroll
    for (int i = 0; i < DEPTH; i++) {
        const float4* wp = (const float4*)(nw + (size_t)node * D);
        double s = 0.0;
#pragma unroll
        for (int k = 0; k < 4; k++) {
            float4 wf = wp[lane + 64 * k];
            s += (double)xf[k].x * (double)wf.x;
            s += (double)xf[k].y * (double)wf.y;
            s += (double)xf[k].z * (double)wf.z;
            s += (double)xf[k].w * (double)wf.w;
        }
#pragma unroll
        for (int m = 32; m >= 1; m >>= 1) s += __shfl_xor(s, m, 64);
        double score = s + (double)nb[node];
        int choice = (score >= 0.0) ? 1 : 0;
        node = 2 * node + 1 + choice;
    }
    int lf = node - N_NODES;
    if (lane == 0) {
        leaf[samp] = lf;
        rnk[samp]  = atomicAdd(&count[lf], 1);
    }
}

// ---------------------------------------------------------------------------
// Kernel 2: exclusive prefix scan over 2048 leaf counts. Single block.
// ---------------------------------------------------------------------------
__global__ __launch_bounds__(256) void scan_kernel(
    const int* __restrict__ count, int* __restrict__ offsets)
{
    __shared__ int tot[256];
    int t = threadIdx.x;
    int c[8], s = 0;
#pragma unroll
    for (int k = 0; k < 8; k++) { c[k] = count[t * 8 + k]; s += c[k]; }
    tot[t] = s;
    __syncthreads();
    for (int off = 1; off < 256; off <<= 1) {
        int v = (t >= off) ? tot[t - off] : 0;
        __syncthreads();
        tot[t] += v;
        __syncthreads();
    }
    int base = (t > 0) ? tot[t - 1] : 0;
#pragma unroll
    for (int k = 0; k < 8; k++) { offsets[t * 8 + k] = base; base += c[k]; }
}

// ---------------------------------------------------------------------------
// Kernel 3: scatter sample ids into per-leaf buckets.
// ---------------------------------------------------------------------------
__global__ __launch_bounds__(256) void scatter_kernel(
    const int* __restrict__ leaf, const int* __restrict__ rnk,
    const int* __restrict__ offsets, int* __restrict__ bucket)
{
    int i = blockIdx.x * 256 + threadIdx.x;
    bucket[offsets[leaf[i]] + rnk[i]] = i;
}

// ---------------------------------------------------------------------------
// Kernel 3b: build work items of <=SMAX samples. item = leaf | (start << 11).
// ---------------------------------------------------------------------------
__global__ __launch_bounds__(256) void build_items_kernel(
    const int* __restrict__ count, int* __restrict__ items,
    int* __restrict__ nitems)
{
    int l = blockIdx.x * 256 + threadIdx.x;
    int c = count[l];
    if (c > 0) {
        int k = (c + SMAX - 1) / SMAX;
        int base = atomicAdd(nitems, k);
        for (int i = 0; i < k; i++)
            items[base + i] = l | ((i * SMAX) << 11);
    }
}

// ---------------------------------------------------------------------------
// DMA helpers: dst is wave-uniform LDS base (HW adds lane*size); src per-lane.
// ---------------------------------------------------------------------------
__device__ __forceinline__ void stage4(const float* src, float* dst, int lane)
{
#pragma unroll
    for (int i = 0; i < 4; i++)
        __builtin_amdgcn_global_load_lds((glb_void*)(src + i * 256 + lane * 4),
                                         (lds_void*)(dst + i * 256), 16, 0, 0);
}

__device__ __forceinline__ void stageL2g(const float* w2w, int cj, float* dst, int lane)
{
#pragma unroll
    for (int jl = 0; jl < 4; jl++)
        __builtin_amdgcn_global_load_lds(
            (glb_void*)(w2w + (size_t)(cj * 4 + jl) * OW + lane * 4),
            (lds_void*)(dst + jl * 256), 16, 0, 0);
}

// 6 loads: x rows s0..s3 (wave's 256-col slice), b1 (128B), b2 slice (1KB)
__device__ __forceinline__ void stageXB(const float* x, const int* sid4,
                                        const float* b1, const float* b2,
                                        float* xsd, float* b1d, float* b2d,
                                        int wave, int lane)
{
#pragma unroll
    for (int s = 0; s < 4; s++)
        __builtin_amdgcn_global_load_lds(
            (glb_void*)(x + (size_t)sid4[s] * D + wave * 256 + lane * 4),
            (lds_void*)(xsd + s * D + wave * 256), 16, 0, 0);
    __builtin_amdgcn_global_load_lds(
        (glb_void*)(b1 + ((lane < 32) ? lane : 31)), (lds_void*)b1d, 4, 0, 0);
    __builtin_amdgcn_global_load_lds(
        (glb_void*)(b2 + wave * 256 + lane * 4), (lds_void*)b2d, 16, 0, 0);
}

// ---------------------------------------------------------------------------
// compute helpers (SS fixed = 4; padded items duplicate the last sample)
// ---------------------------------------------------------------------------
__device__ __forceinline__ void l1c(const float* p, const float* xsw, int c,
                                    int lane, int dg, float4* acc)
{
#pragma unroll
    for (int u = 0; u < 4; u++) {
        float4 w = ((const float4*)p)[u * 64 + lane];
#pragma unroll
        for (int s = 0; s < 4; s++) {
            float xv = xsw[s * D + c * 32 + u * 8 + dg];
            acc[s].x += xv * w.x;
            acc[s].y += xv * w.y;
            acc[s].z += xv * w.z;
            acc[s].w += xv * w.w;
        }
    }
}

__device__ __forceinline__ void l2c(const float* p, const float (*hsv)[32], int cj,
                                    int lane, float4* o)
{
#pragma unroll
    for (int jl = 0; jl < 4; jl++) {
        float4 w = ((const float4*)p)[jl * 64 + lane];
#pragma unroll
        for (int s = 0; s < 4; s++) {
            float hv = hsv[s][cj * 4 + jl];
            o[s].x += hv * w.x;
            o[s].y += hv * w.y;
            o[s].z += hv * w.z;
            o[s].w += hv * w.w;
        }
    }
}

// ---------------------------------------------------------------------------
// Kernel 4: persistent per-item MLP. 512 blocks (2/CU), block b owns items
// b, b+512, ... Cross-item DMA pipeline: groups g14/g15 of item k stage item
// k+1's w1c0/c1 + x/b1/b2, so the per-wave queue never drains. All metadata
// in LDS; biases ride the DMA stream -> zero stray vmem ops, exact vmcnt.
// ---------------------------------------------------------------------------
__global__ __launch_bounds__(256, 2) void mlp_kernel(
    const float* __restrict__ x, const float* __restrict__ w1s,
    const float* __restrict__ b1s, const float* __restrict__ w2s,
    const float* __restrict__ b2s, const int* __restrict__ offsets,
    const int* __restrict__ count, const int* __restrict__ bucket,
    const int* __restrict__ items, const int* __restrict__ nitems,
    float* __restrict__ out)
{
    __shared__ float xs[SMAX * D];          // 16 KB
    __shared__ float wq_[4][2][1024];       // 32 KB: per wave, 2 x 4 KB
    __shared__ float pl1[4][SMAX][32];      // 2 KB
    __shared__ float hs[SMAX][32];          // 0.5 KB
    __shared__ float b1l[2][4][64];         // 2 KB (parity x wave)
    __shared__ float b2l[2][4][256];        // 8 KB (parity x wave)
    __shared__ int   md_leaf[MAXK];
    __shared__ int   md_sid[MAXK][4];

    const int tid = threadIdx.x, lane = tid & 63, wave = tid >> 6;
    const int dg = lane >> 3;
    const int bid = blockIdx.x;

    int nit = nitems[0];
    if (tid < MAXK) {
        int idx = bid + tid * NBLK;
        if (idx < nit) {
            int it = items[idx];
            int l = it & (N_LEAVES - 1), st = it >> 11;
            int c = count[l] - st;
            int S = (c < SMAX) ? c : SMAX;
            int off = offsets[l] + st;
            md_leaf[tid] = l;
            for (int s = 0; s < 4; s++)
                md_sid[tid][s] = bucket[off + ((s < S) ? s : (S - 1))];
        }
    }
    __syncthreads();   // full drain: vmcnt accounting starts at 0 here
    int n_my = (nit - bid + NBLK - 1) >> 9;
    if (n_my <= 0) return;
    if (n_my > MAXK) n_my = MAXK;

    float* WQ0 = &wq_[wave][0][0];
    float* WQ1 = &wq_[wave][1][0];
    const float* xsw = xs + wave * 256;

    // prologue (item 0, parity 0). FIFO: [w1c0(4), xb(6), w1c1(4), pad(4)]
    int lc = md_leaf[0];
    {
        const float* w1w = w1s + (size_t)lc * 32768 + wave * 8192;
        stage4(w1w, WQ0, lane);
        stageXB(x, md_sid[0], b1s + lc * H, b2s + (size_t)lc * OW,
                xs, &b1l[0][wave][0], &b2l[0][wave][0], wave, lane);
        stage4(w1w + 1024, WQ1, lane);
        stage4(w1w + 1024, WQ1, lane);   // pad: same src+dst, benign
    }

    for (int k = 0; k < n_my; k++) {
        const int p  = k & 1;
        const int kn = (k + 1 < n_my) ? (k + 1) : k;   // last: re-stage self
        const int ln = md_leaf[kn];
        const float* w1c = w1s + (size_t)lc * 32768 + wave * 8192;
        const float* w2c = w2s + (size_t)lc * 32768 + wave * 256;
        const float* w1n = w1s + (size_t)ln * 32768 + wave * 8192;
        int sc[4];
#pragma unroll
        for (int s = 0; s < 4; s++) sc[s] = md_sid[k][s];

        float4 acc[4];
#pragma unroll
        for (int s = 0; s < 4; s++) acc[s] = make_float4(0.f, 0.f, 0.f, 0.f);

        // ---- layer 1: groups g0..g7 (stage g+2) ----
        WAITV(8);  l1c(WQ0, xsw, 0, lane, dg, acc); SB; stage4(w1c + 2 * 1024, WQ0, lane);
        WAITV(8);  l1c(WQ1, xsw, 1, lane, dg, acc); SB; stage4(w1c + 3 * 1024, WQ1, lane);
        WAITV(4);  l1c(WQ0, xsw, 2, lane, dg, acc); SB; stage4(w1c + 4 * 1024, WQ0, lane);
        WAITV(4);  l1c(WQ1, xsw, 3, lane, dg, acc); SB; stage4(w1c + 5 * 1024, WQ1, lane);
        WAITV(4);  l1c(WQ0, xsw, 4, lane, dg, acc); SB; stage4(w1c + 6 * 1024, WQ0, lane);
        WAITV(4);  l1c(WQ1, xsw, 5, lane, dg, acc); SB; stage4(w1c + 7 * 1024, WQ1, lane);
        WAITV(4);  l1c(WQ0, xsw, 6, lane, dg, acc); SB; stageL2g(w2c, 0, WQ0, lane);
        WAITV(4);  l1c(WQ1, xsw, 7, lane, dg, acc); SB; stageL2g(w2c, 1, WQ1, lane);

        // reduce over dg (lane bits 3..5), then cross-wave via pl1
#pragma unroll
        for (int m = 8; m <= 32; m <<= 1)
#pragma unroll
            for (int s = 0; s < 4; s++) {
                acc[s].x += __shfl_xor(acc[s].x, m, 64);
                acc[s].y += __shfl_xor(acc[s].y, m, 64);
                acc[s].z += __shfl_xor(acc[s].z, m, 64);
                acc[s].w += __shfl_xor(acc[s].w, m, 64);
            }
        if (dg == 0) {
#pragma unroll
            for (int s = 0; s < 4; s++)
                *(float4*)&pl1[wave][s][(lane & 7) * 4] = acc[s];
        }
        BARRIER;                          // pl1 visible (12 loads in flight)
        if (tid < 128) {
            int s2 = tid >> 5, j2 = tid & 31;
            float sum = pl1[0][s2][j2] + pl1[1][s2][j2] + pl1[2][s2][j2] +
                        pl1[3][s2][j2] + b1l[p][tid >> 6][j2];
            hs[s2][j2] = fmaxf(sum, 0.f);
        }
        BARRIER;                          // hs visible

        float4 o[4];
#pragma unroll
        for (int s = 0; s < 4; s++) o[s] = make_float4(0.f, 0.f, 0.f, 0.f);

        // ---- layer 2: groups g8..g15; g14/g15 stage next item ----
        WAITV(4);  l2c(WQ0, hs, 0, lane, o); SB; stageL2g(w2c, 2, WQ0, lane);
        WAITV(4);  l2c(WQ1, hs, 1, lane, o); SB; stageL2g(w2c, 3, WQ1, lane);
        WAITV(4);  l2c(WQ0, hs, 2, lane, o); SB; stageL2g(w2c, 4, WQ0, lane);
        WAITV(4);  l2c(WQ1, hs, 3, lane, o); SB; stageL2g(w2c, 5, WQ1, lane);
        WAITV(4);  l2c(WQ0, hs, 4, lane, o); SB; stageL2g(w2c, 6, WQ0, lane);
        WAITV(4);  l2c(WQ1, hs, 5, lane, o); SB; stageL2g(w2c, 7, WQ1, lane);
        WAITV(4);  l2c(WQ0, hs, 6, lane, o); SB;
        stage4(w1n, WQ0, lane);                       // next w1c0
        stageXB(x, md_sid[kn], b1s + ln * H, b2s + (size_t)ln * OW,
                xs, &b1l[p ^ 1][wave][0], &b2l[p ^ 1][wave][0], wave, lane);
        WAITV(10); l2c(WQ1, hs, 7, lane, o); SB;
        stage4(w1n + 1024, WQ1, lane);                // next w1c1

        // epilogue: bias + store (padded s rewrites same row, same bytes)
        float4 bv = ((const float4*)&b2l[p][wave][0])[lane];
#pragma unroll
        for (int s = 0; s < 4; s++) {
            float4 o4;
            o4.x = o[s].x + bv.x;
            o4.y = o[s].y + bv.y;
            o4.z = o[s].z + bv.z;
            o4.w = o[s].w + bv.w;
            *(float4*)(out + (size_t)sc[s] * OW + wave * 256 + lane * 4) = o4;
        }
        lc = ln;
    }
}

// ---------------------------------------------------------------------------
extern "C" void kernel_launch(void* const* d_in, const int* in_sizes, int n_in,
                              void* d_out, int out_size, void* d_ws, size_t ws_size,
                              hipStream_t stream)
{
    const float* x   = (const float*)d_in[0];
    const float* nw  = (const float*)d_in[1];
    const float* nb  = (const float*)d_in[2];
    const float* w1s = (const float*)d_in[3];
    const float* b1s = (const float*)d_in[4];
    const float* w2s = (const float*)d_in[5];
    const float* b2s = (const float*)d_in[6];
    float* out = (float*)d_out;

    int* leaf    = (int*)d_ws;
    int* rnk     = leaf + B;
    int* count   = rnk + B;
    int* offsets = count + N_LEAVES;
    int* bucket  = offsets + N_LEAVES;
    int* items   = bucket + B;
    int* nitems  = items + MAX_ITEMS;

    hipMemsetAsync(count, 0, N_LEAVES * sizeof(int), stream);
    hipMemsetAsync(nitems, 0, sizeof(int), stream);
    descent_kernel<<<B / 4, 256, 0, stream>>>(x, nw, nb, leaf, rnk, count);
    scan_kernel<<<1, 256, 0, stream>>>(count, offsets);
    scatter_kernel<<<B / 256, 256, 0, stream>>>(leaf, rnk, offsets, bucket);
    build_items_kernel<<<N_LEAVES / 256, 256, 0, stream>>>(count, items, nitems);
    mlp_kernel<<<NBLK, 256, 0, stream>>>(x, w1s, b1s, w2s, b2s,
                                         offsets, count, bucket,
                                         items, nitems, out);
}

// Round 8
// 128.131 us; speedup vs baseline: 1.0132x; 1.0132x over previous
//
#include <hip/hip_runtime.h>

#define DEPTH 11
#define D 1024
#define H 32
#define OW 1024
#define B 4096
#define N_LEAVES 2048
#define N_NODES 2047
#define SMAX 4
#define MAX_ITEMS 3072
#define NBLK 768
#define MAXK 4   // ceil(MAX_ITEMS / NBLK)

typedef float f32x4 __attribute__((ext_vector_type(4)));
typedef __attribute__((address_space(3))) void lds_void;
typedef const __attribute__((address_space(1))) void glb_void;

#define SB __builtin_amdgcn_sched_barrier(0)
#define WAITV(N) do { asm volatile("s_waitcnt vmcnt(" #N ")" ::: "memory"); SB; } while (0)
#define WAITLG0  do { asm volatile("s_waitcnt lgkmcnt(0)" ::: "memory"); SB; } while (0)
#define BARRIER  do { WAITLG0; __builtin_amdgcn_s_barrier(); \
                      asm volatile("" ::: "memory"); SB; } while (0)
// asm VGPR load: compiler can't sink it (volatile) and can't insert its own
// waits for it (value "defined" by asm) -> we own the vmcnt schedule.
#define GLOAD(dst, ptr) \
    asm volatile("global_load_dwordx4 %0, %1, off" : "=&v"(dst) : "v"(ptr) : "memory")

// ---------------------------------------------------------------------------
// Kernel 1: tree descent. One wave per sample; f64 dot to match the np f64
// reference on the hard >=0 branch decision.
// ---------------------------------------------------------------------------
__global__ __launch_bounds__(256) void descent_kernel(
    const float* __restrict__ x, const float* __restrict__ nw,
    const float* __restrict__ nb, int* __restrict__ leaf,
    int* __restrict__ rnk, int* __restrict__ count)
{
    int lane = threadIdx.x & 63;
    int wv   = threadIdx.x >> 6;
    int samp = blockIdx.x * 4 + wv;

    const float4* xp = (const float4*)(x + (size_t)samp * D);
    float4 xf[4];
#pragma unroll
    for (int k = 0; k < 4; k++) xf[k] = xp[lane + 64 * k];

    int node = 0;
#pragma unroll
    for (int i = 0; i < DEPTH; i++) {
        const float4* wp = (const float4*)(nw + (size_t)node * D);
        double s = 0.0;
#pragma unroll
        for (int k = 0; k < 4; k++) {
            float4 wf = wp[lane + 64 * k];
            s += (double)xf[k].x * (double)wf.x;
            s += (double)xf[k].y * (double)wf.y;
            s += (double)xf[k].z * (double)wf.z;
            s += (double)xf[k].w * (double)wf.w;
        }
#pragma unroll
        for (int m = 32; m >= 1; m >>= 1) s += __shfl_xor(s, m, 64);
        double score = s + (double)nb[node];
        int choice = (score >= 0.0) ? 1 : 0;
        node = 2 * node + 1 + choice;
    }
    int lf = node - N_NODES;
    if (lane == 0) {
        leaf[samp] = lf;
        rnk[samp]  = atomicAdd(&count[lf], 1);
    }
}

// ---------------------------------------------------------------------------
// Kernel 2: exclusive prefix scan over 2048 leaf counts. Single block.
// ---------------------------------------------------------------------------
__global__ __launch_bounds__(256) void scan_kernel(
    const int* __restrict__ count, int* __restrict__ offsets)
{
    __shared__ int tot[256];
    int t = threadIdx.x;
    int c[8], s = 0;
#pragma unroll
    for (int k = 0; k < 8; k++) { c[k] = count[t * 8 + k]; s += c[k]; }
    tot[t] = s;
    __syncthreads();
    for (int off = 1; off < 256; off <<= 1) {
        int v = (t >= off) ? tot[t - off] : 0;
        __syncthreads();
        tot[t] += v;
        __syncthreads();
    }
    int base = (t > 0) ? tot[t - 1] : 0;
#pragma unroll
    for (int k = 0; k < 8; k++) { offsets[t * 8 + k] = base; base += c[k]; }
}

// ---------------------------------------------------------------------------
// Kernel 3: scatter sample ids into per-leaf buckets.
// ---------------------------------------------------------------------------
__global__ __launch_bounds__(256) void scatter_kernel(
    const int* __restrict__ leaf, const int* __restrict__ rnk,
    const int* __restrict__ offsets, int* __restrict__ bucket)
{
    int i = blockIdx.x * 256 + threadIdx.x;
    bucket[offsets[leaf[i]] + rnk[i]] = i;
}

// ---------------------------------------------------------------------------
// Kernel 3b: build work items of <=SMAX samples. item = leaf | (start << 11).
// ---------------------------------------------------------------------------
__global__ __launch_bounds__(256) void build_items_kernel(
    const int* __restrict__ count, int* __restrict__ items,
    int* __restrict__ nitems)
{
    int l = blockIdx.x * 256 + threadIdx.x;
    int c = count[l];
    if (c > 0) {
        int k = (c + SMAX - 1) / SMAX;
        int base = atomicAdd(nitems, k);
        for (int i = 0; i < k; i++)
            items[base + i] = l | ((i * SMAX) << 11);
    }
}

// ---------------------------------------------------------------------------
// Kernel 4: persistent per-item MLP, all-register weight path.
// Per wave: w1 via 8 chunks x 4 asm loads (2-buffer ring, 2 ahead); w2 via
// 32 lane-private asm loads (16-deep rolling window issued from L1 G6 on).
// x + biases ride a 6-load DMA group, counted in the same per-wave FIFO.
// Next item's x/b/w1c0/c1 issue during L2 tail -> pipeline never drains.
// Only block syncs: two raw s_barriers (lgkm-only) around the h-reduce.
// ---------------------------------------------------------------------------
__global__ __launch_bounds__(256, 3) void mlp_kernel(
    const float* __restrict__ x, const float* __restrict__ w1s,
    const float* __restrict__ b1s, const float* __restrict__ w2s,
    const float* __restrict__ b2s, const int* __restrict__ offsets,
    const int* __restrict__ count, const int* __restrict__ bucket,
    const int* __restrict__ items, const int* __restrict__ nitems,
    float* __restrict__ out)
{
    __shared__ __align__(16) float xs[SMAX][D];        // 16 KB
    __shared__ __align__(16) float pl1[4][SMAX][32];   // 2 KB
    __shared__ __align__(16) float hs[SMAX][32];       // 0.5 KB
    __shared__ __align__(16) float b1l[2][4][64];      // 2 KB
    __shared__ __align__(16) float b2l[2][4][256];     // 8 KB
    __shared__ int md_leaf[MAXK];
    __shared__ int md_sid[MAXK][4];

    const int tid = threadIdx.x, lane = tid & 63, wave = tid >> 6;
    const int dg = lane >> 3, lane4 = lane * 4;
    const int bid = blockIdx.x;

    int nit = nitems[0];
    if (tid < MAXK) {
        int idx = bid + tid * NBLK;
        if (idx < nit) {
            int it = items[idx];
            int l = it & (N_LEAVES - 1), st = it >> 11;
            int c = count[l] - st;
            int S = (c < SMAX) ? c : SMAX;
            int off = offsets[l] + st;
            md_leaf[tid] = l;
            for (int s = 0; s < 4; s++)
                md_sid[tid][s] = bucket[off + ((s < S) ? s : (S - 1))];
        }
    }
    __syncthreads();   // full drain: per-wave vmcnt accounting starts at 0
    if (bid >= nit) return;
    int n_my = (nit - bid + NBLK - 1) / NBLK;
    if (n_my > MAXK) n_my = MAXK;

    f32x4 w1r[2][4];
    f32x4 w2r[16];

#define L1I(base, cc, bb) do { _Pragma("unroll") \
    for (int u = 0; u < 4; u++) \
        GLOAD(w1r[bb][u], (base) + (cc) * 1024 + u * 256 + lane4); } while (0)

#define L1C(cc, bb) do { _Pragma("unroll") \
    for (int u = 0; u < 4; u++) { \
        f32x4 wv_ = w1r[bb][u]; \
        _Pragma("unroll") \
        for (int s = 0; s < 4; s++) \
            acc[s] += xs[s][wave * 256 + (cc) * 32 + u * 8 + dg] * wv_; } } while (0)

    // ---- prologue, item 0: FIFO = [xb(6), c0(4), c1(4), c0d(4), c1d(4)] ----
    // (dup c0/c1 pad the FIFO so steady-state WAITV counts hold from item 0;
    //  duplicate loads hit same src/dst regs -> benign.)
    int lc = md_leaf[0];
    const float* w1x = w1s + (size_t)lc * 32768 + wave * 8192;
    {
#pragma unroll
        for (int pp = 0; pp < 4; pp++)
            __builtin_amdgcn_global_load_lds(
                (glb_void*)(x + (size_t)md_sid[0][pp] * D + wave * 256 + lane4),
                (lds_void*)(&xs[pp][wave * 256]), 16, 0, 0);
        __builtin_amdgcn_global_load_lds(
            (glb_void*)(b1s + lc * H + ((lane < 32) ? lane : 31)),
            (lds_void*)(&b1l[0][wave][0]), 4, 0, 0);
        __builtin_amdgcn_global_load_lds(
            (glb_void*)(b2s + (size_t)lc * OW + wave * 256 + lane4),
            (lds_void*)(&b2l[0][wave][0]), 16, 0, 0);
        L1I(w1x, 0, 0); L1I(w1x, 1, 1);
        L1I(w1x, 0, 0); L1I(w1x, 1, 1);   // dup pads
    }

    for (int k = 0; k < n_my; k++) {
        const int p  = k & 1, pn = p ^ 1;
        const int kn = (k + 1 < n_my) ? k + 1 : k;   // last: re-stage self
        const int ln = md_leaf[kn];
        const float* w2x = w2s + (size_t)lc * 32768 + wave * 256;
        const float* w1n = w1s + (size_t)ln * 32768 + wave * 8192;
        int sidc[4];
#pragma unroll
        for (int s = 0; s < 4; s++) sidc[s] = md_sid[k][s];

        f32x4 acc[4] = {};

        // ---- layer 1: wait(c) -> compute(c) -> issue(c+2 / w2 window) ----
        WAITV(8); L1C(0, 0); L1I(w1x, 2, 0);
        WAITV(8); L1C(1, 1); L1I(w1x, 3, 1);
        WAITV(4); L1C(2, 0); L1I(w1x, 4, 0);
        WAITV(4); L1C(3, 1); L1I(w1x, 5, 1);
        WAITV(4); L1C(4, 0); L1I(w1x, 6, 0);
        WAITV(4); L1C(5, 1); L1I(w1x, 7, 1);
        WAITV(4); L1C(6, 0);
#pragma unroll
        for (int j = 0; j < 8; j++) GLOAD(w2r[j], w2x + j * 1024 + lane4);
        WAITV(8); L1C(7, 1);
#pragma unroll
        for (int j = 8; j < 16; j++) GLOAD(w2r[j], w2x + j * 1024 + lane4);

        // reduce over dg (lane bits 3..5), then cross-wave via pl1
#pragma unroll
        for (int m = 8; m <= 32; m <<= 1)
#pragma unroll
            for (int s = 0; s < 4; s++)
#pragma unroll
                for (int e = 0; e < 4; e++)
                    acc[s][e] += __shfl_xor(acc[s][e], m, 64);
        if (dg == 0) {
#pragma unroll
            for (int s = 0; s < 4; s++)
                *(f32x4*)&pl1[wave][s][(lane & 7) * 4] = acc[s];
        }
        BARRIER;                          // pl1 visible (loads stay in flight)
        if (tid < 128) {
            int s2 = tid >> 5, j2 = tid & 31;
            float sum = pl1[0][s2][j2] + pl1[1][s2][j2] + pl1[2][s2][j2] +
                        pl1[3][s2][j2] + b1l[p][tid >> 6][j2];
            hs[s2][j2] = fmaxf(sum, 0.f);
        }
        BARRIER;                          // hs visible

        // ---- layer 2: rolling 16-deep window; tail issues next item ----
        f32x4 o[4] = {};
#pragma unroll
        for (int jj = 0; jj < 32; jj++) {
            if (jj == 31) { WAITV(14); } else { WAITV(15); }
            f32x4 w = w2r[jj & 15];
#pragma unroll
            for (int s = 0; s < 4; s++) o[s] += hs[s][jj] * w;
            if (jj < 16) {
                GLOAD(w2r[jj & 15], w2x + (jj + 16) * 1024 + lane4);
            } else if (jj < 20) {
                const int pp = jj - 16;
                __builtin_amdgcn_global_load_lds(
                    (glb_void*)(x + (size_t)md_sid[kn][pp] * D + wave * 256 + lane4),
                    (lds_void*)(&xs[pp][wave * 256]), 16, 0, 0);
            } else if (jj == 20) {
                __builtin_amdgcn_global_load_lds(
                    (glb_void*)(b1s + ln * H + ((lane < 32) ? lane : 31)),
                    (lds_void*)(&b1l[pn][wave][0]), 4, 0, 0);
            } else if (jj == 21) {
                __builtin_amdgcn_global_load_lds(
                    (glb_void*)(b2s + (size_t)ln * OW + wave * 256 + lane4),
                    (lds_void*)(&b2l[pn][wave][0]), 16, 0, 0);
            } else if (jj < 26) {
                GLOAD(w1r[0][jj - 22], w1n + (jj - 22) * 256 + lane4);
            } else if (jj < 30) {
                GLOAD(w1r[1][jj - 26], w1n + 1024 + (jj - 26) * 256 + lane4);
            }
        }

        // epilogue: bias + store (padded s rewrites same row, same bytes)
        f32x4 bv = *(const f32x4*)&b2l[p][wave][lane4];
#pragma unroll
        for (int s = 0; s < 4; s++) {
            f32x4 ov = o[s] + bv;
            *(f32x4*)(out + (size_t)sidc[s] * OW + wave * 256 + lane4) = ov;
        }
        lc = ln;
        w1x = w1n;
    }
#undef L1I
#undef L1C
}

// ---------------------------------------------------------------------------
extern "C" void kernel_launch(void* const* d_in, const int* in_sizes, int n_in,
                              void* d_out, int out_size, void* d_ws, size_t ws_size,
                              hipStream_t stream)
{
    const float* x   = (const float*)d_in[0];
    const float* nw  = (const float*)d_in[1];
    const float* nb  = (const float*)d_in[2];
    const float* w1s = (const float*)d_in[3];
    const float* b1s = (const float*)d_in[4];
    const float* w2s = (const float*)d_in[5];
    const float* b2s = (const float*)d_in[6];
    float* out = (float*)d_out;

    int* leaf    = (int*)d_ws;
    int* rnk     = leaf + B;
    int* count   = rnk + B;
    int* offsets = count + N_LEAVES;
    int* bucket  = offsets + N_LEAVES;
    int* items   = bucket + B;
    int* nitems  = items + MAX_ITEMS;

    hipMemsetAsync(count, 0, N_LEAVES * sizeof(int), stream);
    hipMemsetAsync(nitems, 0, sizeof(int), stream);
    descent_kernel<<<B / 4, 256, 0, stream>>>(x, nw, nb, leaf, rnk, count);
    scan_kernel<<<1, 256, 0, stream>>>(count, offsets);
    scatter_kernel<<<B / 256, 256, 0, stream>>>(leaf, rnk, offsets, bucket);
    build_items_kernel<<<N_LEAVES / 256, 256, 0, stream>>>(count, items, nitems);
    mlp_kernel<<<NBLK, 256, 0, stream>>>(x, w1s, b1s, w2s, b2s,
                                         offsets, count, bucket,
                                         items, nitems, out);
}

// Round 9
// 125.003 us; speedup vs baseline: 1.0386x; 1.0250x over previous
//
#include <hip/hip_runtime.h>

#define DEPTH 11
#define D 1024
#define H 32
#define OW 1024
#define B 4096
#define N_LEAVES 2048
#define N_NODES 2047
#define SMAX 4
#define MAX_ITEMS 3072
#define NBLK 768
#define MAXK 4   // ceil(MAX_ITEMS / NBLK)

typedef float f32x4 __attribute__((ext_vector_type(4)));
typedef __attribute__((address_space(3))) void lds_void;
typedef const __attribute__((address_space(1))) void glb_void;

#define SB __builtin_amdgcn_sched_barrier(0)
#define WAITV(N) do { asm volatile("s_waitcnt vmcnt(" #N ")" ::: "memory"); SB; } while (0)
#define WAITLG0  do { asm volatile("s_waitcnt lgkmcnt(0)" ::: "memory"); SB; } while (0)
#define BARRIER  do { WAITLG0; __builtin_amdgcn_s_barrier(); \
                      asm volatile("" ::: "memory"); SB; } while (0)
#define GLOAD(dst, ptr) \
    asm volatile("global_load_dwordx4 %0, %1, off" : "=&v"(dst) : "v"(ptr) : "memory")

// ---------------------------------------------------------------------------
// Kernel 1: tree descent. One wave per sample; f64 dot to match the np f64
// reference on the hard >=0 branch decision.
// ---------------------------------------------------------------------------
__global__ __launch_bounds__(256) void descent_kernel(
    const float* __restrict__ x, const float* __restrict__ nw,
    const float* __restrict__ nb, int* __restrict__ leaf,
    int* __restrict__ rnk, int* __restrict__ count)
{
    int lane = threadIdx.x & 63;
    int wv   = threadIdx.x >> 6;
    int samp = blockIdx.x * 4 + wv;

    const float4* xp = (const float4*)(x + (size_t)samp * D);
    float4 xf[4];
#pragma unroll
    for (int k = 0; k < 4; k++) xf[k] = xp[lane + 64 * k];

    int node = 0;
#pragma unroll
    for (int i = 0; i < DEPTH; i++) {
        const float4* wp = (const float4*)(nw + (size_t)node * D);
        double s = 0.0;
#pragma unroll
        for (int k = 0; k < 4; k++) {
            float4 wf = wp[lane + 64 * k];
            s += (double)xf[k].x * (double)wf.x;
            s += (double)xf[k].y * (double)wf.y;
            s += (double)xf[k].z * (double)wf.z;
            s += (double)xf[k].w * (double)wf.w;
        }
#pragma unroll
        for (int m = 32; m >= 1; m >>= 1) s += __shfl_xor(s, m, 64);
        double score = s + (double)nb[node];
        int choice = (score >= 0.0) ? 1 : 0;
        node = 2 * node + 1 + choice;
    }
    int lf = node - N_NODES;
    if (lane == 0) {
        leaf[samp] = lf;
        rnk[samp]  = atomicAdd(&count[lf], 1);
    }
}

// ---------------------------------------------------------------------------
// Kernel 2: fused scan + item build. Single block: exclusive prefix scan of
// 2048 counts -> offsets, and emit work items of <=SMAX samples.
// ---------------------------------------------------------------------------
__global__ __launch_bounds__(256) void scanbuild_kernel(
    const int* __restrict__ count, int* __restrict__ offsets,
    int* __restrict__ items, int* __restrict__ nitems)
{
    __shared__ int tot[256];
    __shared__ int ln;
    int t = threadIdx.x;
    if (t == 0) ln = 0;
    int c[8], s = 0;
#pragma unroll
    for (int k = 0; k < 8; k++) { c[k] = count[t * 8 + k]; s += c[k]; }
    tot[t] = s;
    __syncthreads();
    for (int off = 1; off < 256; off <<= 1) {
        int v = (t >= off) ? tot[t - off] : 0;
        __syncthreads();
        tot[t] += v;
        __syncthreads();
    }
    int base = (t > 0) ? tot[t - 1] : 0;
    int myit = 0;
#pragma unroll
    for (int k = 0; k < 8; k++) myit += (c[k] + SMAX - 1) / SMAX;
    int ibase = (myit > 0) ? atomicAdd(&ln, myit) : 0;
#pragma unroll
    for (int k = 0; k < 8; k++) {
        offsets[t * 8 + k] = base;
        int ki = (c[k] + SMAX - 1) / SMAX;
        for (int i = 0; i < ki; i++)
            items[ibase++] = (t * 8 + k) | ((i * SMAX) << 11);
        base += c[k];
    }
    __syncthreads();
    if (t == 0) nitems[0] = ln;
}

// ---------------------------------------------------------------------------
// Kernel 3: scatter sample ids into per-leaf buckets.
// ---------------------------------------------------------------------------
__global__ __launch_bounds__(256) void scatter_kernel(
    const int* __restrict__ leaf, const int* __restrict__ rnk,
    const int* __restrict__ offsets, int* __restrict__ bucket)
{
    int i = blockIdx.x * 256 + threadIdx.x;
    bucket[offsets[leaf[i]] + rnk[i]] = i;
}

// ---------------------------------------------------------------------------
// Kernel 4: persistent per-item MLP, all-register weight path, ONE barrier
// per item. After the pl1 barrier each wave computes the full h redundantly
// into wave-private LDS (2 values/lane) -> no second barrier. pl1 is parity
// double-buffered so the single-barrier flow has no cross-item race.
// vmcnt FIFO (per wave, steady loop top): [xb6, c0:4, c1:4, stores:4] = 18.
// ---------------------------------------------------------------------------
__global__ __launch_bounds__(256, 3) void mlp_kernel(
    const float* __restrict__ x, const float* __restrict__ w1s,
    const float* __restrict__ b1s, const float* __restrict__ w2s,
    const float* __restrict__ b2s, const int* __restrict__ offsets,
    const int* __restrict__ count, const int* __restrict__ bucket,
    const int* __restrict__ items, const int* __restrict__ nitems,
    float* __restrict__ out)
{
    __shared__ __align__(16) float xs[SMAX][D];          // 16 KB
    __shared__ __align__(16) float pl1[2][4][SMAX][32];  // 4 KB (parity!)
    __shared__ __align__(16) float hs_w[4][SMAX][32];    // 2 KB wave-private
    __shared__ __align__(16) float b1l[2][4][64];        // 2 KB
    __shared__ __align__(16) float b2l[2][4][256];       // 8 KB
    __shared__ int md_leaf[MAXK];
    __shared__ int md_sid[MAXK][4];

    const int tid = threadIdx.x, lane = tid & 63, wave = tid >> 6;
    const int dg = lane >> 3, lane4 = lane * 4;
    const int bid = blockIdx.x;

    int nit = nitems[0];
    if (tid < MAXK) {
        int idx = bid + tid * NBLK;
        if (idx < nit) {
            int it = items[idx];
            int l = it & (N_LEAVES - 1), st = it >> 11;
            int c = count[l] - st;
            int S = (c < SMAX) ? c : SMAX;
            int off = offsets[l] + st;
            md_leaf[tid] = l;
            for (int s = 0; s < 4; s++)
                md_sid[tid][s] = bucket[off + ((s < S) ? s : (S - 1))];
        }
    }
    __syncthreads();   // full drain: per-wave vmcnt accounting starts at 0
    if (bid >= nit) return;
    int n_my = (nit - bid + NBLK - 1) / NBLK;
    if (n_my > MAXK) n_my = MAXK;

    f32x4 w1r[2][4];
    f32x4 w2r[16];

#define L1I(base, cc, bb) do { _Pragma("unroll") \
    for (int u = 0; u < 4; u++) \
        GLOAD(w1r[bb][u], (base) + (cc) * 1024 + u * 256 + lane4); } while (0)

#define L1C(cc, bb) do { _Pragma("unroll") \
    for (int u = 0; u < 4; u++) { \
        f32x4 wv_ = w1r[bb][u]; \
        _Pragma("unroll") \
        for (int s = 0; s < 4; s++) \
            acc[s] += xs[s][wave * 256 + (cc) * 32 + u * 8 + dg] * wv_; } } while (0)

#define STAGE_X(KK, PP) \
    __builtin_amdgcn_global_load_lds( \
        (glb_void*)(x + (size_t)md_sid[KK][PP] * D + wave * 256 + lane4), \
        (lds_void*)(&xs[PP][wave * 256]), 16, 0, 0)
#define STAGE_B1(LL, PP) \
    __builtin_amdgcn_global_load_lds( \
        (glb_void*)(b1s + (LL) * H + ((lane < 32) ? lane : 31)), \
        (lds_void*)(&b1l[PP][wave][0]), 4, 0, 0)
#define STAGE_B2(LL, PP) \
    __builtin_amdgcn_global_load_lds( \
        (glb_void*)(b2s + (size_t)(LL) * OW + wave * 256 + lane4), \
        (lds_void*)(&b2l[PP][wave][0]), 16, 0, 0)

    // ---- prologue, item 0: FIFO = [xb(6), c0(4), c1(4), c1dup(4)] = 18 ----
    int lc = md_leaf[0];
    const float* w1x = w1s + (size_t)lc * 32768 + wave * 8192;
    {
        STAGE_X(0, 0); STAGE_X(0, 1); STAGE_X(0, 2); STAGE_X(0, 3);
        STAGE_B1(lc, 0); STAGE_B2(lc, 0);
        L1I(w1x, 0, 0); L1I(w1x, 1, 1);
        L1I(w1x, 1, 1);   // dup pad -> mirrors steady-state store slot
    }

    for (int k = 0; k < n_my; k++) {
        const int p  = k & 1, pn = p ^ 1;
        const int kn = (k + 1 < n_my) ? k + 1 : k;   // last: re-stage self
        const int ln = md_leaf[kn];
        const float* w2x = w2s + (size_t)lc * 32768 + wave * 256;
        const float* w1n = w1s + (size_t)ln * 32768 + wave * 8192;
        int sidc[4];
#pragma unroll
        for (int s = 0; s < 4; s++) sidc[s] = md_sid[k][s];

        f32x4 acc[4] = {};

        // ---- layer 1: wait(chunk) -> compute -> issue(chunk+2 / w2) ----
        WAITV(8); L1C(0, 0); SB; L1I(w1x, 2, 0);
        WAITV(8); L1C(1, 1); SB; L1I(w1x, 3, 1);
        WAITV(4); L1C(2, 0); SB; L1I(w1x, 4, 0);
        WAITV(4); L1C(3, 1); SB; L1I(w1x, 5, 1);
        WAITV(4); L1C(4, 0); SB; L1I(w1x, 6, 0);
        WAITV(4); L1C(5, 1); SB; L1I(w1x, 7, 1);
        WAITV(4); L1C(6, 0); SB;
#pragma unroll
        for (int j = 0; j < 8; j++) GLOAD(w2r[j], w2x + j * 1024 + lane4);
        WAITV(8); L1C(7, 1); SB;
#pragma unroll
        for (int j = 8; j < 16; j++) GLOAD(w2r[j], w2x + j * 1024 + lane4);

        // reduce over dg (lane bits 3..5) within the wave
#pragma unroll
        for (int m = 8; m <= 32; m <<= 1)
#pragma unroll
            for (int s = 0; s < 4; s++)
#pragma unroll
                for (int e = 0; e < 4; e++)
                    acc[s][e] += __shfl_xor(acc[s][e], m, 64);
        if (dg == 0) {
#pragma unroll
            for (int s = 0; s < 4; s++)
                *(f32x4*)&pl1[p][wave][s][(lane & 7) * 4] = acc[s];
        }
        BARRIER;   // the ONLY barrier per item (16 w2 loads ride through)

        // wave-private h: each lane finalizes 2 of the 128 h values
        {
            int v = lane * 2, s2 = v >> 5, j2 = v & 31;
            float ha = pl1[p][0][s2][j2] + pl1[p][1][s2][j2] +
                       pl1[p][2][s2][j2] + pl1[p][3][s2][j2] + b1l[p][wave][j2];
            float hb = pl1[p][0][s2][j2 + 1] + pl1[p][1][s2][j2 + 1] +
                       pl1[p][2][s2][j2 + 1] + pl1[p][3][s2][j2 + 1] +
                       b1l[p][wave][j2 + 1];
            float2 hv;
            hv.x = fmaxf(ha, 0.f);
            hv.y = fmaxf(hb, 0.f);
            *(float2*)&hs_w[wave][s2][j2] = hv;
        }
        WAITLG0;   // wave-local: hs_w visible to this wave (no barrier)

        const float(*hw)[32] = hs_w[wave];
        f32x4 o[4] = {};

#define L2CMP(JJ) do { f32x4 w_ = w2r[(JJ) & 15]; _Pragma("unroll") \
    for (int s = 0; s < 4; s++) o[s] += hw[s][JJ] * w_; } while (0)

        // ---- layer 2: 32 steps, 16-deep window; tail issues next item ----
        WAITV(15); L2CMP(0);  SB; GLOAD(w2r[0],  w2x + 16 * 1024 + lane4);
        WAITV(15); L2CMP(1);  SB; GLOAD(w2r[1],  w2x + 17 * 1024 + lane4);
        WAITV(15); L2CMP(2);  SB; GLOAD(w2r[2],  w2x + 18 * 1024 + lane4);
        WAITV(15); L2CMP(3);  SB; GLOAD(w2r[3],  w2x + 19 * 1024 + lane4);
        WAITV(15); L2CMP(4);  SB; GLOAD(w2r[4],  w2x + 20 * 1024 + lane4);
        WAITV(15); L2CMP(5);  SB; GLOAD(w2r[5],  w2x + 21 * 1024 + lane4);
        WAITV(15); L2CMP(6);  SB; GLOAD(w2r[6],  w2x + 22 * 1024 + lane4);
        WAITV(15); L2CMP(7);  SB; GLOAD(w2r[7],  w2x + 23 * 1024 + lane4);
        WAITV(15); L2CMP(8);  SB; GLOAD(w2r[8],  w2x + 24 * 1024 + lane4);
        WAITV(15); L2CMP(9);  SB; GLOAD(w2r[9],  w2x + 25 * 1024 + lane4);
        WAITV(15); L2CMP(10); SB; GLOAD(w2r[10], w2x + 26 * 1024 + lane4);
        WAITV(15); L2CMP(11); SB; GLOAD(w2r[11], w2x + 27 * 1024 + lane4);
        WAITV(15); L2CMP(12); SB; GLOAD(w2r[12], w2x + 28 * 1024 + lane4);
        WAITV(15); L2CMP(13); SB; GLOAD(w2r[13], w2x + 29 * 1024 + lane4);
        WAITV(15); L2CMP(14); SB; GLOAD(w2r[14], w2x + 30 * 1024 + lane4);
        WAITV(15); L2CMP(15); SB; GLOAD(w2r[15], w2x + 31 * 1024 + lane4);
        WAITV(15); L2CMP(16); SB; STAGE_X(kn, 0);
        WAITV(15); L2CMP(17); SB; STAGE_X(kn, 1);
        WAITV(15); L2CMP(18); SB; STAGE_X(kn, 2);
        WAITV(15); L2CMP(19); SB; STAGE_X(kn, 3);
        WAITV(15); L2CMP(20); SB; STAGE_B1(ln, pn);
        WAITV(15); L2CMP(21); SB; STAGE_B2(ln, pn);
        WAITV(15); L2CMP(22); SB; L1I(w1n, 0, 0);
        WAITV(18); L2CMP(23); SB; L1I(w1n, 1, 1);
        WAITV(21); L2CMP(24); SB;
        WAITV(20); L2CMP(25); SB;
        WAITV(19); L2CMP(26); SB;
        WAITV(18); L2CMP(27); SB;
        WAITV(17); L2CMP(28); SB;
        WAITV(16); L2CMP(29); SB;
        WAITV(15); L2CMP(30); SB;
        WAITV(14); L2CMP(31); SB;
#undef L2CMP

        // epilogue: bias + store (stores join the vmcnt FIFO: +4 -> 18)
        f32x4 bv = *(const f32x4*)&b2l[p][wave][lane4];
#pragma unroll
        for (int s = 0; s < 4; s++) {
            f32x4 ov = o[s] + bv;
            *(f32x4*)(out + (size_t)sidc[s] * OW + wave * 256 + lane4) = ov;
        }
        lc = ln;
        w1x = w1n;
    }
#undef L1I
#undef L1C
#undef STAGE_X
#undef STAGE_B1
#undef STAGE_B2
}

// ---------------------------------------------------------------------------
extern "C" void kernel_launch(void* const* d_in, const int* in_sizes, int n_in,
                              void* d_out, int out_size, void* d_ws, size_t ws_size,
                              hipStream_t stream)
{
    const float* x   = (const float*)d_in[0];
    const float* nw  = (const float*)d_in[1];
    const float* nb  = (const float*)d_in[2];
    const float* w1s = (const float*)d_in[3];
    const float* b1s = (const float*)d_in[4];
    const float* w2s = (const float*)d_in[5];
    const float* b2s = (const float*)d_in[6];
    float* out = (float*)d_out;

    int* leaf    = (int*)d_ws;
    int* rnk     = leaf + B;
    int* count   = rnk + B;
    int* offsets = count + N_LEAVES;
    int* bucket  = offsets + N_LEAVES;
    int* items   = bucket + B;
    int* nitems  = items + MAX_ITEMS;

    hipMemsetAsync(count, 0, N_LEAVES * sizeof(int), stream);
    descent_kernel<<<B / 4, 256, 0, stream>>>(x, nw, nb, leaf, rnk, count);
    scanbuild_kernel<<<1, 256, 0, stream>>>(count, offsets, items, nitems);
    scatter_kernel<<<B / 256, 256, 0, stream>>>(leaf, rnk, offsets, bucket);
    mlp_kernel<<<NBLK, 256, 0, stream>>>(x, w1s, b1s, w2s, b2s,
                                         offsets, count, bucket,
                                         items, nitems, out);
}